// Round 1
// baseline (299.784 us; speedup 1.0000x reference)
//
#include <hip/hip_runtime.h>

// Reference epilogue: y = clip(min(y, 0.25), 0.25, 1.0)  ==  0.25 for all
// finite y. Conv3d + bias + GroupNorm output is always finite with these
// inputs, so the whole network collapses to a constant fill of 0.25f over
// the output tensor [8, 32, 62, 62, 62] (61,011,968 fp32 elements).
//
// Pure write-bound kernel: float4 stores (16 B/lane), coalesced, no reads.

__global__ __launch_bounds__(256) void fill_quarter_kernel(float* __restrict__ out,
                                                           long long n) {
    long long i4 = (long long)blockIdx.x * blockDim.x + threadIdx.x;
    long long base = i4 * 4;
    if (base + 3 < n) {
        float4 v = make_float4(0.25f, 0.25f, 0.25f, 0.25f);
        *reinterpret_cast<float4*>(out + base) = v;
    } else if (base < n) {
        for (long long j = base; j < n; ++j) out[j] = 0.25f;
    }
}

extern "C" void kernel_launch(void* const* d_in, const int* in_sizes, int n_in,
                              void* d_out, int out_size, void* d_ws, size_t ws_size,
                              hipStream_t stream) {
    (void)d_in; (void)in_sizes; (void)n_in; (void)d_ws; (void)ws_size;
    float* out = (float*)d_out;
    long long n = (long long)out_size;           // 61,011,968
    long long n4 = (n + 3) / 4;                  // float4 groups
    int block = 256;
    long long grid = (n4 + block - 1) / block;
    fill_quarter_kernel<<<(unsigned)grid, block, 0, stream>>>(out, n);
}